// Round 4
// baseline (415.224 us; speedup 1.0000x reference)
//
#include <hip/hip_runtime.h>
#include <math.h>

#define NPTS 16384
#define NH   32
#define NC   128
#define NK   43

typedef __attribute__((ext_vector_type(8))) short short8;
typedef __attribute__((ext_vector_type(4))) float f32x4;

// ---------------- workspace layout (float indices) ----------------
enum : int {
  OFF_W1T  = 0,         // 16384
  OFF_W3T  = 16384,     // 16384
  OFF_CWPK = 32768,     // 4096 floats (1024 x uint4): conv_w bf16 B-fragments
  OFF_KPF  = 36864,     // 256 (192 used): kernel points in A-frag k-order
  OFF_SC1  = 37120, OFF_SH1 = 37248,
  OFF_SC2  = 37376, OFF_SH2 = 37504,
  OFF_SC3  = 37632, OFF_SH3 = 37760,
  OFF_PART = 37888,     // 512*256 f32 partials (reused by all 3 BN stages)
  OFF_A    = 168960,    // N*C floats
  OFF_B    = 168960 + NPTS*NC,
};
// F (packed bf16 features, 1M uints = 4 MB) lives in d_out's feat section,
// which is dead until final_out_kernel overwrites it at the end.

struct KPArgs { float p[NK * 3]; };   // 516 B, computed on host, baked into graph

// =================== host-side kernel-point computation ===================
static void host_make_kp(float* kp) {
  unsigned int mt[624];
  mt[0] = 42u;
  for (int i = 1; i < 624; ++i)
    mt[i] = 1812433253u * (mt[i-1] ^ (mt[i-1] >> 30)) + (unsigned)i;
  int pos = 624;
  auto next = [&]() -> unsigned int {
    if (pos == 624) {
      for (int i = 0; i < 624; ++i) {
        unsigned int y = (mt[i] & 0x80000000u) | (mt[(i+1)%624] & 0x7fffffffu);
        unsigned int v = mt[(i+397)%624] ^ (y >> 1);
        if (y & 1u) v ^= 0x9908b0dfu;
        mt[i] = v;
      }
      pos = 0;
    }
    unsigned int y = mt[pos++];
    y ^= y >> 11;
    y ^= (y << 7)  & 0x9d2c5680u;
    y ^= (y << 15) & 0xefc60000u;
    y ^= y >> 18;
    return y;
  };
  auto rdouble = [&]() -> double {
    unsigned int a = next() >> 5, b = next() >> 6;
    return ((double)a * 67108864.0 + (double)b) / 9007199254740992.0;
  };
  double gcache = 0.0; bool has_g = false;
  auto gauss = [&]() -> double {
    if (has_g) { has_g = false; return gcache; }
    double x1, x2, r2;
    do {
      x1 = 2.0 * rdouble() - 1.0;
      x2 = 2.0 * rdouble() - 1.0;
      r2 = x1*x1 + x2*x2;
    } while (r2 >= 1.0 || r2 == 0.0);
    double f = sqrt(-2.0 * log(r2) / r2);
    gcache = f * x1; has_g = true;
    return f * x2;
  };
  double g[126];
  for (int i = 0; i < 126; ++i) g[i] = gauss();
  kp[0] = 0.f; kp[1] = 0.f; kp[2] = 0.f;
  for (int r = 0; r < 14; ++r) {
    double x = g[r*3], y = g[r*3+1], z = g[r*3+2];
    double nrm = sqrt(x*x + y*y + z*z);
    kp[(1+r)*3+0] = (float)(x / nrm * 0.5);
    kp[(1+r)*3+1] = (float)(y / nrm * 0.5);
    kp[(1+r)*3+2] = (float)(z / nrm * 0.5);
  }
  for (int r = 0; r < 28; ++r) {
    double x = g[42+r*3], y = g[42+r*3+1], z = g[42+r*3+2];
    double nrm = sqrt(x*x + y*y + z*z);
    kp[(15+r)*3+0] = (float)(x / nrm);
    kp[(15+r)*3+1] = (float)(y / nrm);
    kp[(15+r)*3+2] = (float)(z / nrm);
  }
}

__device__ __forceinline__ unsigned short f2bf(float f) {   // RNE (cold paths)
  unsigned u = __float_as_uint(f);
  return (unsigned short)((u + 0x7FFFu + ((u >> 16) & 1u)) >> 16);
}

// =================== prep: W transposes + conv_w B-frags + kp A-order =====
__global__ __launch_bounds__(256) void prep_kernel(
    const float* __restrict__ w1, const float* __restrict__ w3,
    const float* __restrict__ cw, KPArgs kpa,
    float* __restrict__ w1t, float* __restrict__ w3t,
    uint4* __restrict__ cwpk, float* __restrict__ kpf) {
  int idx = blockIdx.x * 256 + threadIdx.x;
  if (idx < 2*NC*NC) {
    int m = idx >> 14, k = (idx >> 7) & 127, c = idx & 127;
    (m ? w3t : w1t)[k*NC + c] = (m ? w3 : w1)[c*NC + k];
  } else if (idx < 2*NC*NC + 1024) {
    int t = idx - 2*NC*NC;
    int f = t >> 6, l = t & 63;
    int ks = f >> 3, nt = f & 7, g = l >> 4, li = l & 15;
    int c = nt*16 + li, k0 = ks*32 + g*8;
    float v[8];
    #pragma unroll
    for (int i = 0; i < 8; ++i) {
      int k = k0 + i;
      v[i] = (k < NK) ? cw[k*NC + c] : 0.f;
    }
    uint4 q;
    q.x = (unsigned)f2bf(v[0]) | ((unsigned)f2bf(v[1]) << 16);
    q.y = (unsigned)f2bf(v[2]) | ((unsigned)f2bf(v[3]) << 16);
    q.z = (unsigned)f2bf(v[4]) | ((unsigned)f2bf(v[5]) << 16);
    q.w = (unsigned)f2bf(v[6]) | ((unsigned)f2bf(v[7]) << 16);
    cwpk[f*64 + l] = q;
  } else if (idx < 2*NC*NC + 1024 + 192) {
    int t = idx - (2*NC*NC + 1024);
    int comp = t >> 6, slot = t & 63;
    kpf[comp*64 + slot] = ( (slot) < NK ? 0.f : 0.f, 0.f );  // placeholder, overwritten below
    int ks = slot >> 5, g = (slot >> 3) & 3, i = slot & 7;
    int k = ks*32 + g*8 + i;
    kpf[comp*64 + slot] = (k < NK) ? kpa.p[k*3 + comp] : 1e9f;
  }
}

// =================== GEMM + fused per-block BN stats ======================
// BN==1: apply relu(in*sc+sh) while staging into LDS (fuses BN2-apply)
// Always writes per-block channel partial sums/sumsq to part[bid*256 + {c|128+c}]
template<int BN>
__global__ __launch_bounds__(256) void gemm128(
    const float* __restrict__ A, const float* __restrict__ Wt,
    const float* __restrict__ sc, const float* __restrict__ sh,
    float* __restrict__ out, float* __restrict__ part) {
  __shared__ float a_s[32][NC];
  int row0 = blockIdx.x * 32;
  const float4* A4 = (const float4*)(A + (size_t)row0 * NC);
  float4* as4 = (float4*)&a_s[0][0];
  if (BN) {
    int c4 = (threadIdx.x & 31) << 2;
    float4 s = *(const float4*)(sc + c4);
    float4 h = *(const float4*)(sh + c4);
    for (int i = threadIdx.x; i < 32 * 32; i += 256) {
      float4 v = A4[i];
      v.x = fmaxf(0.f, fmaf(v.x, s.x, h.x));
      v.y = fmaxf(0.f, fmaf(v.y, s.y, h.y));
      v.z = fmaxf(0.f, fmaf(v.z, s.z, h.z));
      v.w = fmaxf(0.f, fmaf(v.w, s.w, h.w));
      as4[i] = v;
    }
  } else {
    for (int i = threadIdx.x; i < 32 * 32; i += 256) as4[i] = A4[i];
  }
  __syncthreads();

  int lane = threadIdx.x & 31;
  int g    = threadIdx.x >> 5;
  const float4* W4 = (const float4*)Wt;

  float4 acc[4];
  #pragma unroll
  for (int r = 0; r < 4; ++r) acc[r] = make_float4(0.f, 0.f, 0.f, 0.f);

  for (int k0 = 0; k0 < NC; k0 += 4) {
    float4 w0 = W4[(k0+0)*32 + lane];
    float4 w1 = W4[(k0+1)*32 + lane];
    float4 w2 = W4[(k0+2)*32 + lane];
    float4 w3 = W4[(k0+3)*32 + lane];
    #pragma unroll
    for (int r = 0; r < 4; ++r) {
      float4 a = *(const float4*)&a_s[g*4 + r][k0];
      acc[r].x = fmaf(a.x, w0.x, acc[r].x); acc[r].y = fmaf(a.x, w0.y, acc[r].y);
      acc[r].z = fmaf(a.x, w0.z, acc[r].z); acc[r].w = fmaf(a.x, w0.w, acc[r].w);
      acc[r].x = fmaf(a.y, w1.x, acc[r].x); acc[r].y = fmaf(a.y, w1.y, acc[r].y);
      acc[r].z = fmaf(a.y, w1.z, acc[r].z); acc[r].w = fmaf(a.y, w1.w, acc[r].w);
      acc[r].x = fmaf(a.z, w2.x, acc[r].x); acc[r].y = fmaf(a.z, w2.y, acc[r].y);
      acc[r].z = fmaf(a.z, w2.z, acc[r].z); acc[r].w = fmaf(a.z, w2.w, acc[r].w);
      acc[r].x = fmaf(a.w, w3.x, acc[r].x); acc[r].y = fmaf(a.w, w3.y, acc[r].y);
      acc[r].z = fmaf(a.w, w3.z, acc[r].z); acc[r].w = fmaf(a.w, w3.w, acc[r].w);
    }
  }
  #pragma unroll
  for (int r = 0; r < 4; ++r)
    ((float4*)(out + (size_t)(row0 + g*4 + r) * NC))[lane] = acc[r];

  // ---- fused per-block BN stats (sum, sumsq over this block's 32 rows) ----
  __syncthreads();                       // a_s reads done; reuse as scratch
  float* ls = &a_s[0][0];                // [8][128] sums
  float* lq = ls + 1024;                 // [8][128] sumsqs
  float sx = acc[0].x+acc[1].x+acc[2].x+acc[3].x;
  float sy = acc[0].y+acc[1].y+acc[2].y+acc[3].y;
  float sz = acc[0].z+acc[1].z+acc[2].z+acc[3].z;
  float sw = acc[0].w+acc[1].w+acc[2].w+acc[3].w;
  float qx = acc[0].x*acc[0].x+acc[1].x*acc[1].x+acc[2].x*acc[2].x+acc[3].x*acc[3].x;
  float qy = acc[0].y*acc[0].y+acc[1].y*acc[1].y+acc[2].y*acc[2].y+acc[3].y*acc[3].y;
  float qz = acc[0].z*acc[0].z+acc[1].z*acc[1].z+acc[2].z*acc[2].z+acc[3].z*acc[3].z;
  float qw = acc[0].w*acc[0].w+acc[1].w*acc[1].w+acc[2].w*acc[2].w+acc[3].w*acc[3].w;
  int col = lane * 4;
  ls[g*128+col+0]=sx; ls[g*128+col+1]=sy; ls[g*128+col+2]=sz; ls[g*128+col+3]=sw;
  lq[g*128+col+0]=qx; lq[g*128+col+1]=qy; lq[g*128+col+2]=qz; lq[g*128+col+3]=qw;
  __syncthreads();
  int t = threadIdx.x;
  float v = 0.f;
  if (t < 128) {
    #pragma unroll
    for (int gg = 0; gg < 8; ++gg) v += ls[gg*128 + t];
  } else {
    int c = t - 128;
    #pragma unroll
    for (int gg = 0; gg < 8; ++gg) v += lq[gg*128 + c];
  }
  part[(size_t)blockIdx.x * 256 + t] = v;
}

// =================== BN stats (f32 partials) for kpconv output =============
__global__ __launch_bounds__(128) void bn_stats(
    const float* __restrict__ x, float* __restrict__ part) {
  int c = threadIdx.x;
  int row0 = blockIdx.x * 64;
  float s = 0.f, q = 0.f;
  for (int r = 0; r < 64; ++r) {
    float v = x[(size_t)(row0 + r) * NC + c];
    s += v;
    q = fmaf(v, v, q);
  }
  part[(size_t)blockIdx.x * 256 + c]       = s;
  part[(size_t)blockIdx.x * 256 + 128 + c] = q;
}

__global__ void bn_final(const float* __restrict__ part, int nb,
                         const float* __restrict__ g, const float* __restrict__ b,
                         float* __restrict__ sc, float* __restrict__ sh) {
  int c = threadIdx.x;
  double s = 0.0, q = 0.0;
  for (int i = 0; i < nb; ++i) {
    s += (double)part[(size_t)i * 256 + c];
    q += (double)part[(size_t)i * 256 + 128 + c];
  }
  double mean = s * (1.0 / (double)NPTS);
  double var  = q * (1.0 / (double)NPTS) - mean * mean;
  double rstd = 1.0 / sqrt(var + 1e-5);
  double scale = (double)g[c] * rstd;
  sc[c] = (float)scale;
  sh[c] = (float)((double)b[c] - mean * scale);
}

// ====== BN1-apply + ReLU + bf16 pair-pack: F[n][li*4+nt] = (c, c+64) ======
__global__ __launch_bounds__(256) void bn1_pack(
    const float* __restrict__ A, const float* __restrict__ sc,
    const float* __restrict__ sh, unsigned* __restrict__ F) {
  int t = blockIdx.x * 256 + threadIdx.x;     // 0 .. NPTS*64-1
  int n = t >> 6, w = t & 63;
  int li = w >> 2, nt = w & 3;
  int c = nt*16 + li;
  const float* row = A + (size_t)n * NC;
  float a = fmaxf(0.f, fmaf(row[c],      sc[c],      sh[c]));
  float b = fmaxf(0.f, fmaf(row[c + 64], sc[c + 64], sh[c + 64]));
  F[t] = (unsigned)f2bf(a) | ((unsigned)f2bf(b) << 16);
}

// =================== KPConv via MFMA, packed-bf16 feature gather ===========
__global__ __launch_bounds__(256) void kpconv_kernel(
    const float* __restrict__ coord, const int* __restrict__ ref,
    const unsigned* __restrict__ F, const uint4* __restrict__ cwpk,
    const float* __restrict__ kpf, float* __restrict__ y)
{
  int l  = threadIdx.x & 63;
  int n  = blockIdx.x * 4 + (threadIdx.x >> 6);
  int g  = l >> 4, li = l & 15;

  float cx = coord[n*3+0], cy = coord[n*3+1], cz = coord[n*3+2];
  int j = ref[(size_t)n * NH + (l & 31)];
  bool shadow = ((unsigned)j >= (unsigned)NPTS);
  int jc = shadow ? 0 : j;
  float qx = shadow ? 1e6f : coord[jc*3+0];
  float qy = shadow ? 1e6f : coord[jc*3+1];
  float qz = shadow ? 1e6f : coord[jc*3+2];
  float px = qx - cx, py = qy - cy, pz = qz - cz;

  float p0x = __shfl(px, li),      p0y = __shfl(py, li),      p0z = __shfl(pz, li);
  float p1x = __shfl(px, li + 16), p1y = __shfl(py, li + 16), p1z = __shfl(pz, li + 16);

  // A fragments: infl[h][k] bf16 (truncating convert), lane covers k=ks*32+g*8+i
  short8 afr[2][2];   // [mt][ks]
  #pragma unroll
  for (int ks = 0; ks < 2; ++ks) {
    const float4* kbx = (const float4*)(kpf +   0 + (ks*4+g)*8);
    const float4* kby = (const float4*)(kpf +  64 + (ks*4+g)*8);
    const float4* kbz = (const float4*)(kpf + 128 + (ks*4+g)*8);
    float4 x0 = kbx[0], x1 = kbx[1];
    float4 y0 = kby[0], y1 = kby[1];
    float4 z0 = kbz[0], z1 = kbz[1];
    float kx[8] = {x0.x,x0.y,x0.z,x0.w,x1.x,x1.y,x1.z,x1.w};
    float ky[8] = {y0.x,y0.y,y0.z,y0.w,y1.x,y1.y,y1.z,y1.w};
    float kz[8] = {z0.x,z0.y,z0.z,z0.w,z1.x,z1.y,z1.z,z1.w};
    #pragma unroll
    for (int mt = 0; mt < 2; ++mt) {
      float fx = mt ? p1x : p0x, fy = mt ? p1y : p0y, fz = mt ? p1z : p0z;
      short8 af;
      #pragma unroll
      for (int i = 0; i < 8; ++i) {
        float dx = fx - kx[i], dy = fy - ky[i], dz = fz - kz[i];
        float d2 = fmaf(dx, dx, fmaf(dy, dy, dz*dz));
        float iv = fmaxf(1.f - sqrtf(d2), 0.f);
        af[i] = (short)(__float_as_uint(iv) >> 16);   // truncating bf16
      }
      afr[mt][ks] = af;
    }
  }

  // s[mt][nt] = infl @ conv_w
  f32x4 acc[2][8];
  #pragma unroll
  for (int mt = 0; mt < 2; ++mt)
    #pragma unroll
    for (int nt = 0; nt < 8; ++nt)
      acc[mt][nt] = (f32x4){0.f, 0.f, 0.f, 0.f};

  #pragma unroll
  for (int nt = 0; nt < 8; ++nt) {
    uint4 b0 = cwpk[(0*8 + nt)*64 + l];
    uint4 b1 = cwpk[(1*8 + nt)*64 + l];
    union { uint4 u; short8 s; } c0, c1;
    c0.u = b0; c1.u = b1;
    #pragma unroll
    for (int mt = 0; mt < 2; ++mt) {
      acc[mt][nt] = __builtin_amdgcn_mfma_f32_16x16x32_bf16(afr[mt][0], c0.s, acc[mt][nt], 0, 0, 0);
      acc[mt][nt] = __builtin_amdgcn_mfma_f32_16x16x32_bf16(afr[mt][1], c1.s, acc[mt][nt], 0, 0, 0);
    }
  }

  // apply: out[c] = sum_h s[h][c] * fbn1[j(h)][c]   (features pre-BN'd, bf16 pairs)
  const uint4* F4 = (const uint4*)F;
  float outp[8];
  #pragma unroll
  for (int p = 0; p < 8; ++p) outp[p] = 0.f;

  #pragma unroll
  for (int mt = 0; mt < 2; ++mt) {
    uint4 fq[4];
    #pragma unroll
    for (int r = 0; r < 4; ++r) {
      int h = mt*16 + g*4 + r;
      int jh = __shfl(j, h);
      int jhc = ((unsigned)jh >= (unsigned)NPTS) ? 0 : jh;   // s==0 for shadow
      fq[r] = F4[(size_t)jhc * 16 + li];
    }
    #pragma unroll
    for (int r = 0; r < 4; ++r) {
      unsigned uu[4] = {fq[r].x, fq[r].y, fq[r].z, fq[r].w};
      #pragma unroll
      for (int p = 0; p < 4; ++p) {
        float flo = __uint_as_float(uu[p] << 16);
        float fhi = __uint_as_float(uu[p] & 0xffff0000u);
        outp[p]     = fmaf(acc[mt][p][r],     flo, outp[p]);
        outp[p + 4] = fmaf(acc[mt][p + 4][r], fhi, outp[p + 4]);
      }
    }
  }

  #pragma unroll
  for (int p = 0; p < 8; ++p) {
    outp[p] += __shfl_xor(outp[p], 16);
    outp[p] += __shfl_xor(outp[p], 32);
  }
  float o0 = (g == 0) ? outp[0] : (g == 1) ? outp[1] : (g == 2) ? outp[2] : outp[3];
  float o1 = (g == 0) ? outp[4] : (g == 1) ? outp[5] : (g == 2) ? outp[6] : outp[7];
  y[(size_t)n * NC + l]      = o0;
  y[(size_t)n * NC + 64 + l] = o1;
}

// =================== final: out = relu(identity + z*sc + sh) + coord/offset =
__global__ __launch_bounds__(256) void final_out_kernel(
    const float* __restrict__ feat, const float* __restrict__ z,
    const float* __restrict__ sc, const float* __restrict__ sh,
    const float* __restrict__ coord, const int* __restrict__ offs,
    float* __restrict__ out) {
  int i = blockIdx.x * 256 + threadIdx.x;
  if (i < NPTS * NC / 4) {
    float4 f = ((const float4*)feat)[i];
    float4 v = ((const float4*)z)[i];
    int c = (i & 31) << 2;
    v.x = fmaxf(0.f, f.x + fmaf(v.x, sc[c+0], sh[c+0]));
    v.y = fmaxf(0.f, f.y + fmaf(v.y, sc[c+1], sh[c+1]));
    v.z = fmaxf(0.f, f.z + fmaf(v.z, sc[c+2], sh[c+2]));
    v.w = fmaxf(0.f, f.w + fmaf(v.w, sc[c+3], sh[c+3]));
    ((float4*)out)[NPTS*3/4 + i] = v;
  } else {
    int ci = i - NPTS * NC / 4;
    if (ci < NPTS*3/4) ((float4*)out)[ci] = ((const float4*)coord)[ci];
    if (ci == 0) out[NPTS*3 + (size_t)NPTS*NC] = (float)offs[0];
  }
}

// =========================================================================
extern "C" void kernel_launch(void* const* d_in, const int* in_sizes, int n_in,
                              void* d_out, int out_size, void* d_ws, size_t ws_size,
                              hipStream_t stream) {
  (void)in_sizes; (void)n_in; (void)out_size; (void)ws_size;
  const float* coord = (const float*)d_in[0];
  const float* feat  = (const float*)d_in[1];
  const int*   offs  = (const int*)d_in[2];
  const int*   ref   = (const int*)d_in[3];
  const float* w1    = (const float*)d_in[4];
  const float* w3    = (const float*)d_in[5];
  const float* cw    = (const float*)d_in[6];
  const float* g1 = (const float*)d_in[7],  *b1 = (const float*)d_in[8];
  const float* g2 = (const float*)d_in[9],  *b2 = (const float*)d_in[10];
  const float* g3 = (const float*)d_in[11], *b3 = (const float*)d_in[12];

  float* ws  = (float*)d_ws;
  float* out = (float*)d_out;
  float* w1t = ws + OFF_W1T;
  float* w3t = ws + OFF_W3T;
  uint4* cwpk = (uint4*)(ws + OFF_CWPK);
  float* kpf = ws + OFF_KPF;
  float* sc1 = ws + OFF_SC1, *sh1 = ws + OFF_SH1;
  float* sc2 = ws + OFF_SC2, *sh2 = ws + OFF_SH2;
  float* sc3 = ws + OFF_SC3, *sh3 = ws + OFF_SH3;
  float* part = ws + OFF_PART;
  float* A = ws + OFF_A;
  float* B = ws + OFF_B;
  unsigned* F = (unsigned*)(out + NPTS*3);    // scratch in d_out's feat section

  KPArgs kpa;
  host_make_kp(kpa.p);

  prep_kernel<<<133, 256, 0, stream>>>(w1, w3, cw, kpa, w1t, w3t, cwpk, kpf);

  // fc1 (stats fused) -> finalize -> BN1-apply+ReLU+bf16-pack
  gemm128<0><<<NPTS/32, 256, 0, stream>>>(feat, w1t, nullptr, nullptr, A, part);
  bn_final<<<1, 128, 0, stream>>>(part, NPTS/32, g1, b1, sc1, sh1);
  bn1_pack<<<NPTS*64/256, 256, 0, stream>>>(A, sc1, sh1, F);

  // KPConv (MFMA, packed gather)
  kpconv_kernel<<<NPTS/4, 256, 0, stream>>>(coord, ref, F, cwpk, kpf, B);

  // BN2 stats -> finalize (apply fused into fc3 LDS stage)
  bn_stats<<<256, 128, 0, stream>>>(B, part);
  bn_final<<<1, 128, 0, stream>>>(part, 256, g2, b2, sc2, sh2);

  // fc3 (BN2-apply fused, stats fused) -> finalize
  gemm128<1><<<NPTS/32, 256, 0, stream>>>(B, w3t, sc2, sh2, A, part);
  bn_final<<<1, 128, 0, stream>>>(part, NPTS/32, g3, b3, sc3, sh3);

  // residual + ReLU + coord + offset
  final_out_kernel<<<(NPTS*NC/4 + NPTS*3/4 + 255)/256, 256, 0, stream>>>(
      feat, A, sc3, sh3, coord, offs, out);
}

// Round 5
// 110.241 us; speedup vs baseline: 3.7665x; 3.7665x over previous
//
#include <hip/hip_runtime.h>
#include <math.h>

#define NPTS 16384
#define NH   32
#define NC   128
#define NK   43

typedef __attribute__((ext_vector_type(8))) short short8;
typedef __attribute__((ext_vector_type(4))) float f32x4;

// ---------------- workspace layout (float indices) ----------------
enum : int {
  OFF_W1T  = 0,         // 16384
  OFF_W3T  = 16384,     // 16384
  OFF_CWPK = 32768,     // 4096 floats (1024 x uint4): conv_w bf16 B-fragments
  OFF_KPF  = 36864,     // 256 (192 used): kernel points in A-frag k-order
  OFF_SC1  = 37120, OFF_SH1 = 37248,
  OFF_SC2  = 37376, OFF_SH2 = 37504,
  OFF_SC3  = 37632, OFF_SH3 = 37760,
  OFF_PART = 37888,     // 512*256 f32 partials (reused by all 3 BN stages)
  OFF_A    = 168960,    // N*C floats
  OFF_B    = 168960 + NPTS*NC,
};
// F (packed bf16 features, 1M uints = 4 MB) lives in d_out's feat section,
// which is dead until final_out_kernel overwrites it at the end.

struct KPArgs { float p[NK * 3]; };   // 516 B, computed on host, baked into graph

// =================== host-side kernel-point computation ===================
static void host_make_kp(float* kp) {
  unsigned int mt[624];
  mt[0] = 42u;
  for (int i = 1; i < 624; ++i)
    mt[i] = 1812433253u * (mt[i-1] ^ (mt[i-1] >> 30)) + (unsigned)i;
  int pos = 624;
  auto next = [&]() -> unsigned int {
    if (pos == 624) {
      for (int i = 0; i < 624; ++i) {
        unsigned int y = (mt[i] & 0x80000000u) | (mt[(i+1)%624] & 0x7fffffffu);
        unsigned int v = mt[(i+397)%624] ^ (y >> 1);
        if (y & 1u) v ^= 0x9908b0dfu;
        mt[i] = v;
      }
      pos = 0;
    }
    unsigned int y = mt[pos++];
    y ^= y >> 11;
    y ^= (y << 7)  & 0x9d2c5680u;
    y ^= (y << 15) & 0xefc60000u;
    y ^= y >> 18;
    return y;
  };
  auto rdouble = [&]() -> double {
    unsigned int a = next() >> 5, b = next() >> 6;
    return ((double)a * 67108864.0 + (double)b) / 9007199254740992.0;
  };
  double gcache = 0.0; bool has_g = false;
  auto gauss = [&]() -> double {
    if (has_g) { has_g = false; return gcache; }
    double x1, x2, r2;
    do {
      x1 = 2.0 * rdouble() - 1.0;
      x2 = 2.0 * rdouble() - 1.0;
      r2 = x1*x1 + x2*x2;
    } while (r2 >= 1.0 || r2 == 0.0);
    double f = sqrt(-2.0 * log(r2) / r2);
    gcache = f * x1; has_g = true;
    return f * x2;
  };
  double g[126];
  for (int i = 0; i < 126; ++i) g[i] = gauss();
  kp[0] = 0.f; kp[1] = 0.f; kp[2] = 0.f;
  for (int r = 0; r < 14; ++r) {
    double x = g[r*3], y = g[r*3+1], z = g[r*3+2];
    double nrm = sqrt(x*x + y*y + z*z);
    kp[(1+r)*3+0] = (float)(x / nrm * 0.5);
    kp[(1+r)*3+1] = (float)(y / nrm * 0.5);
    kp[(1+r)*3+2] = (float)(z / nrm * 0.5);
  }
  for (int r = 0; r < 28; ++r) {
    double x = g[42+r*3], y = g[42+r*3+1], z = g[42+r*3+2];
    double nrm = sqrt(x*x + y*y + z*z);
    kp[(15+r)*3+0] = (float)(x / nrm);
    kp[(15+r)*3+1] = (float)(y / nrm);
    kp[(15+r)*3+2] = (float)(z / nrm);
  }
}

__device__ __forceinline__ unsigned short f2bf(float f) {   // RNE (cold paths)
  unsigned u = __float_as_uint(f);
  return (unsigned short)((u + 0x7FFFu + ((u >> 16) & 1u)) >> 16);
}

// =================== prep: W transposes + conv_w B-frags + kp A-order =====
__global__ __launch_bounds__(256) void prep_kernel(
    const float* __restrict__ w1, const float* __restrict__ w3,
    const float* __restrict__ cw, KPArgs kpa,
    float* __restrict__ w1t, float* __restrict__ w3t,
    uint4* __restrict__ cwpk, float* __restrict__ kpf) {
  int idx = blockIdx.x * 256 + threadIdx.x;
  if (idx < 2*NC*NC) {
    int m = idx >> 14, k = (idx >> 7) & 127, c = idx & 127;
    (m ? w3t : w1t)[k*NC + c] = (m ? w3 : w1)[c*NC + k];
  } else if (idx < 2*NC*NC + 1024) {
    int t = idx - 2*NC*NC;
    int f = t >> 6, l = t & 63;
    int ks = f >> 3, nt = f & 7, g = l >> 4, li = l & 15;
    int c = nt*16 + li, k0 = ks*32 + g*8;
    float v[8];
    #pragma unroll
    for (int i = 0; i < 8; ++i) {
      int k = k0 + i;
      v[i] = (k < NK) ? cw[k*NC + c] : 0.f;
    }
    uint4 q;
    q.x = (unsigned)f2bf(v[0]) | ((unsigned)f2bf(v[1]) << 16);
    q.y = (unsigned)f2bf(v[2]) | ((unsigned)f2bf(v[3]) << 16);
    q.z = (unsigned)f2bf(v[4]) | ((unsigned)f2bf(v[5]) << 16);
    q.w = (unsigned)f2bf(v[6]) | ((unsigned)f2bf(v[7]) << 16);
    cwpk[f*64 + l] = q;
  } else if (idx < 2*NC*NC + 1024 + 192) {
    int t = idx - (2*NC*NC + 1024);
    int comp = t >> 6, slot = t & 63;
    int ks = slot >> 5, g = (slot >> 3) & 3, i = slot & 7;
    int k = ks*32 + g*8 + i;
    kpf[comp*64 + slot] = (k < NK) ? kpa.p[k*3 + comp] : 1e9f;
  }
}

// =================== GEMM + fused per-block BN stats ======================
// BN==1: apply relu(in*sc+sh) while staging into LDS (fuses BN2-apply)
// Always writes per-block channel partial sums/sumsq to part[bid*256 + {c|128+c}]
template<int BN>
__global__ __launch_bounds__(256) void gemm128(
    const float* __restrict__ A, const float* __restrict__ Wt,
    const float* __restrict__ sc, const float* __restrict__ sh,
    float* __restrict__ out, float* __restrict__ part) {
  __shared__ float a_s[32][NC];
  int row0 = blockIdx.x * 32;
  const float4* A4 = (const float4*)(A + (size_t)row0 * NC);
  float4* as4 = (float4*)&a_s[0][0];
  if (BN) {
    int c4 = (threadIdx.x & 31) << 2;
    float4 s = *(const float4*)(sc + c4);
    float4 h = *(const float4*)(sh + c4);
    for (int i = threadIdx.x; i < 32 * 32; i += 256) {
      float4 v = A4[i];
      v.x = fmaxf(0.f, fmaf(v.x, s.x, h.x));
      v.y = fmaxf(0.f, fmaf(v.y, s.y, h.y));
      v.z = fmaxf(0.f, fmaf(v.z, s.z, h.z));
      v.w = fmaxf(0.f, fmaf(v.w, s.w, h.w));
      as4[i] = v;
    }
  } else {
    for (int i = threadIdx.x; i < 32 * 32; i += 256) as4[i] = A4[i];
  }
  __syncthreads();

  int lane = threadIdx.x & 31;
  int g    = threadIdx.x >> 5;
  const float4* W4 = (const float4*)Wt;

  float4 acc[4];
  #pragma unroll
  for (int r = 0; r < 4; ++r) acc[r] = make_float4(0.f, 0.f, 0.f, 0.f);

  for (int k0 = 0; k0 < NC; k0 += 4) {
    float4 w0 = W4[(k0+0)*32 + lane];
    float4 w1 = W4[(k0+1)*32 + lane];
    float4 w2 = W4[(k0+2)*32 + lane];
    float4 w3 = W4[(k0+3)*32 + lane];
    #pragma unroll
    for (int r = 0; r < 4; ++r) {
      float4 a = *(const float4*)&a_s[g*4 + r][k0];
      acc[r].x = fmaf(a.x, w0.x, acc[r].x); acc[r].y = fmaf(a.x, w0.y, acc[r].y);
      acc[r].z = fmaf(a.x, w0.z, acc[r].z); acc[r].w = fmaf(a.x, w0.w, acc[r].w);
      acc[r].x = fmaf(a.y, w1.x, acc[r].x); acc[r].y = fmaf(a.y, w1.y, acc[r].y);
      acc[r].z = fmaf(a.y, w1.z, acc[r].z); acc[r].w = fmaf(a.y, w1.w, acc[r].w);
      acc[r].x = fmaf(a.z, w2.x, acc[r].x); acc[r].y = fmaf(a.z, w2.y, acc[r].y);
      acc[r].z = fmaf(a.z, w2.z, acc[r].z); acc[r].w = fmaf(a.z, w2.w, acc[r].w);
      acc[r].x = fmaf(a.w, w3.x, acc[r].x); acc[r].y = fmaf(a.w, w3.y, acc[r].y);
      acc[r].z = fmaf(a.w, w3.z, acc[r].z); acc[r].w = fmaf(a.w, w3.w, acc[r].w);
    }
  }
  #pragma unroll
  for (int r = 0; r < 4; ++r)
    ((float4*)(out + (size_t)(row0 + g*4 + r) * NC))[lane] = acc[r];

  // ---- fused per-block BN stats (sum, sumsq over this block's 32 rows) ----
  __syncthreads();                       // a_s reads done; reuse as scratch
  float* ls = &a_s[0][0];                // [8][128] sums
  float* lq = ls + 1024;                 // [8][128] sumsqs
  float sx = acc[0].x+acc[1].x+acc[2].x+acc[3].x;
  float sy = acc[0].y+acc[1].y+acc[2].y+acc[3].y;
  float sz = acc[0].z+acc[1].z+acc[2].z+acc[3].z;
  float sw = acc[0].w+acc[1].w+acc[2].w+acc[3].w;
  float qx = acc[0].x*acc[0].x+acc[1].x*acc[1].x+acc[2].x*acc[2].x+acc[3].x*acc[3].x;
  float qy = acc[0].y*acc[0].y+acc[1].y*acc[1].y+acc[2].y*acc[2].y+acc[3].y*acc[3].y;
  float qz = acc[0].z*acc[0].z+acc[1].z*acc[1].z+acc[2].z*acc[2].z+acc[3].z*acc[3].z;
  float qw = acc[0].w*acc[0].w+acc[1].w*acc[1].w+acc[2].w*acc[2].w+acc[3].w*acc[3].w;
  int col = lane * 4;
  ls[g*128+col+0]=sx; ls[g*128+col+1]=sy; ls[g*128+col+2]=sz; ls[g*128+col+3]=sw;
  lq[g*128+col+0]=qx; lq[g*128+col+1]=qy; lq[g*128+col+2]=qz; lq[g*128+col+3]=qw;
  __syncthreads();
  int t = threadIdx.x;
  float v = 0.f;
  if (t < 128) {
    #pragma unroll
    for (int gg = 0; gg < 8; ++gg) v += ls[gg*128 + t];
  } else {
    int c = t - 128;
    #pragma unroll
    for (int gg = 0; gg < 8; ++gg) v += lq[gg*128 + c];
  }
  part[(size_t)blockIdx.x * 256 + t] = v;
}

// =================== BN stats (f32 partials) for kpconv output =============
__global__ __launch_bounds__(128) void bn_stats(
    const float* __restrict__ x, float* __restrict__ part) {
  int c = threadIdx.x;
  int row0 = blockIdx.x * 64;
  float s = 0.f, q = 0.f;
  for (int r = 0; r < 64; ++r) {
    float v = x[(size_t)(row0 + r) * NC + c];
    s += v;
    q = fmaf(v, v, q);
  }
  part[(size_t)blockIdx.x * 256 + c]       = s;
  part[(size_t)blockIdx.x * 256 + 128 + c] = q;
}

// ====== parallel BN finalize: 1024 threads = 8 slices x 128 channels ======
template<int NB>
__global__ __launch_bounds__(1024) void bn_final(
    const float* __restrict__ part,
    const float* __restrict__ g, const float* __restrict__ b,
    float* __restrict__ sc, float* __restrict__ sh) {
  __shared__ float ls[8][128], lq[8][128];
  int c  = threadIdx.x & 127;
  int sl = threadIdx.x >> 7;            // 0..7
  constexpr int PER = NB / 8;
  int i0 = sl * PER;
  float s = 0.f, q = 0.f;
  #pragma unroll 8
  for (int i = 0; i < PER; ++i) {
    s += part[(size_t)(i0 + i) * 256 + c];
    q += part[(size_t)(i0 + i) * 256 + 128 + c];
  }
  ls[sl][c] = s; lq[sl][c] = q;
  __syncthreads();
  if (threadIdx.x < 128) {
    double S = 0.0, Q = 0.0;
    #pragma unroll
    for (int k = 0; k < 8; ++k) { S += (double)ls[k][c]; Q += (double)lq[k][c]; }
    double mean = S * (1.0 / (double)NPTS);
    double var  = Q * (1.0 / (double)NPTS) - mean * mean;
    double rstd = 1.0 / sqrt(var + 1e-5);
    double scale = (double)g[c] * rstd;
    sc[c] = (float)scale;
    sh[c] = (float)((double)b[c] - mean * scale);
  }
}

// ====== BN1-apply + ReLU + bf16 pair-pack: F[n][li*4+nt] = (c, c+64) ======
__global__ __launch_bounds__(256) void bn1_pack(
    const float* __restrict__ A, const float* __restrict__ sc,
    const float* __restrict__ sh, unsigned* __restrict__ F) {
  int t = blockIdx.x * 256 + threadIdx.x;     // 0 .. NPTS*64-1
  int n = t >> 6, w = t & 63;
  int li = w >> 2, nt = w & 3;
  int c = nt*16 + li;
  const float* row = A + (size_t)n * NC;
  float a = fmaxf(0.f, fmaf(row[c],      sc[c],      sh[c]));
  float b = fmaxf(0.f, fmaf(row[c + 64], sc[c + 64], sh[c + 64]));
  F[t] = (unsigned)f2bf(a) | ((unsigned)f2bf(b) << 16);
}

// =================== KPConv via MFMA, packed-bf16 feature gather ===========
__global__ __launch_bounds__(256) void kpconv_kernel(
    const float* __restrict__ coord, const int* __restrict__ ref,
    const unsigned* __restrict__ F, const uint4* __restrict__ cwpk,
    const float* __restrict__ kpf, float* __restrict__ y)
{
  int l  = threadIdx.x & 63;
  int n  = blockIdx.x * 4 + (threadIdx.x >> 6);
  int g  = l >> 4, li = l & 15;

  float cx = coord[n*3+0], cy = coord[n*3+1], cz = coord[n*3+2];
  int j = ref[(size_t)n * NH + (l & 31)];
  bool shadow = ((unsigned)j >= (unsigned)NPTS);
  int jc = shadow ? 0 : j;
  float qx = shadow ? 1e6f : coord[jc*3+0];
  float qy = shadow ? 1e6f : coord[jc*3+1];
  float qz = shadow ? 1e6f : coord[jc*3+2];
  float px = qx - cx, py = qy - cy, pz = qz - cz;

  float p0x = __shfl(px, li),      p0y = __shfl(py, li),      p0z = __shfl(pz, li);
  float p1x = __shfl(px, li + 16), p1y = __shfl(py, li + 16), p1z = __shfl(pz, li + 16);

  // A fragments: infl[h][k] bf16 (truncating convert), lane covers k=ks*32+g*8+i
  short8 afr[2][2];   // [mt][ks]
  #pragma unroll
  for (int ks = 0; ks < 2; ++ks) {
    const float4* kbx = (const float4*)(kpf +   0 + (ks*4+g)*8);
    const float4* kby = (const float4*)(kpf +  64 + (ks*4+g)*8);
    const float4* kbz = (const float4*)(kpf + 128 + (ks*4+g)*8);
    float4 x0 = kbx[0], x1 = kbx[1];
    float4 y0 = kby[0], y1 = kby[1];
    float4 z0 = kbz[0], z1 = kbz[1];
    float kx[8] = {x0.x,x0.y,x0.z,x0.w,x1.x,x1.y,x1.z,x1.w};
    float ky[8] = {y0.x,y0.y,y0.z,y0.w,y1.x,y1.y,y1.z,y1.w};
    float kz[8] = {z0.x,z0.y,z0.z,z0.w,z1.x,z1.y,z1.z,z1.w};
    #pragma unroll
    for (int mt = 0; mt < 2; ++mt) {
      float fx = mt ? p1x : p0x, fy = mt ? p1y : p0y, fz = mt ? p1z : p0z;
      short8 af;
      #pragma unroll
      for (int i = 0; i < 8; ++i) {
        float dx = fx - kx[i], dy = fy - ky[i], dz = fz - kz[i];
        float d2 = fmaf(dx, dx, fmaf(dy, dy, dz*dz));
        float iv = fmaxf(1.f - sqrtf(d2), 0.f);
        af[i] = (short)(__float_as_uint(iv) >> 16);   // truncating bf16
      }
      afr[mt][ks] = af;
    }
  }

  // s[mt][nt] = infl @ conv_w
  f32x4 acc[2][8];
  #pragma unroll
  for (int mt = 0; mt < 2; ++mt)
    #pragma unroll
    for (int nt = 0; nt < 8; ++nt)
      acc[mt][nt] = (f32x4){0.f, 0.f, 0.f, 0.f};

  #pragma unroll
  for (int nt = 0; nt < 8; ++nt) {
    uint4 b0 = cwpk[(0*8 + nt)*64 + l];
    uint4 b1 = cwpk[(1*8 + nt)*64 + l];
    union { uint4 u; short8 s; } c0, c1;
    c0.u = b0; c1.u = b1;
    #pragma unroll
    for (int mt = 0; mt < 2; ++mt) {
      acc[mt][nt] = __builtin_amdgcn_mfma_f32_16x16x32_bf16(afr[mt][0], c0.s, acc[mt][nt], 0, 0, 0);
      acc[mt][nt] = __builtin_amdgcn_mfma_f32_16x16x32_bf16(afr[mt][1], c1.s, acc[mt][nt], 0, 0, 0);
    }
  }

  // apply: out[c] = sum_h s[h][c] * fbn1[j(h)][c]   (features pre-BN'd, bf16 pairs)
  const uint4* F4 = (const uint4*)F;
  float outp[8];
  #pragma unroll
  for (int p = 0; p < 8; ++p) outp[p] = 0.f;

  #pragma unroll
  for (int mt = 0; mt < 2; ++mt) {
    uint4 fq[4];
    #pragma unroll
    for (int r = 0; r < 4; ++r) {
      int h = mt*16 + g*4 + r;
      int jh = __shfl(j, h);
      int jhc = ((unsigned)jh >= (unsigned)NPTS) ? 0 : jh;   // s==0 for shadow
      fq[r] = F4[(size_t)jhc * 16 + li];
    }
    #pragma unroll
    for (int r = 0; r < 4; ++r) {
      unsigned uu[4] = {fq[r].x, fq[r].y, fq[r].z, fq[r].w};
      #pragma unroll
      for (int p = 0; p < 4; ++p) {
        float flo = __uint_as_float(uu[p] << 16);
        float fhi = __uint_as_float(uu[p] & 0xffff0000u);
        outp[p]     = fmaf(acc[mt][p][r],     flo, outp[p]);
        outp[p + 4] = fmaf(acc[mt][p + 4][r], fhi, outp[p + 4]);
      }
    }
  }

  #pragma unroll
  for (int p = 0; p < 8; ++p) {
    outp[p] += __shfl_xor(outp[p], 16);
    outp[p] += __shfl_xor(outp[p], 32);
  }
  float o0 = (g == 0) ? outp[0] : (g == 1) ? outp[1] : (g == 2) ? outp[2] : outp[3];
  float o1 = (g == 0) ? outp[4] : (g == 1) ? outp[5] : (g == 2) ? outp[6] : outp[7];
  y[(size_t)n * NC + l]      = o0;
  y[(size_t)n * NC + 64 + l] = o1;
}

// =================== final: out = relu(identity + z*sc + sh) + coord/offset =
__global__ __launch_bounds__(256) void final_out_kernel(
    const float* __restrict__ feat, const float* __restrict__ z,
    const float* __restrict__ sc, const float* __restrict__ sh,
    const float* __restrict__ coord, const int* __restrict__ offs,
    float* __restrict__ out) {
  int i = blockIdx.x * 256 + threadIdx.x;
  if (i < NPTS * NC / 4) {
    float4 f = ((const float4*)feat)[i];
    float4 v = ((const float4*)z)[i];
    int c = (i & 31) << 2;
    v.x = fmaxf(0.f, f.x + fmaf(v.x, sc[c+0], sh[c+0]));
    v.y = fmaxf(0.f, f.y + fmaf(v.y, sc[c+1], sh[c+1]));
    v.z = fmaxf(0.f, f.z + fmaf(v.z, sc[c+2], sh[c+2]));
    v.w = fmaxf(0.f, f.w + fmaf(v.w, sc[c+3], sh[c+3]));
    ((float4*)out)[NPTS*3/4 + i] = v;
  } else {
    int ci = i - NPTS * NC / 4;
    if (ci < NPTS*3/4) ((float4*)out)[ci] = ((const float4*)coord)[ci];
    if (ci == 0) out[NPTS*3 + (size_t)NPTS*NC] = (float)offs[0];
  }
}

// =========================================================================
extern "C" void kernel_launch(void* const* d_in, const int* in_sizes, int n_in,
                              void* d_out, int out_size, void* d_ws, size_t ws_size,
                              hipStream_t stream) {
  (void)in_sizes; (void)n_in; (void)out_size; (void)ws_size;
  const float* coord = (const float*)d_in[0];
  const float* feat  = (const float*)d_in[1];
  const int*   offs  = (const int*)d_in[2];
  const int*   ref   = (const int*)d_in[3];
  const float* w1    = (const float*)d_in[4];
  const float* w3    = (const float*)d_in[5];
  const float* cw    = (const float*)d_in[6];
  const float* g1 = (const float*)d_in[7],  *b1 = (const float*)d_in[8];
  const float* g2 = (const float*)d_in[9],  *b2 = (const float*)d_in[10];
  const float* g3 = (const float*)d_in[11], *b3 = (const float*)d_in[12];

  float* ws  = (float*)d_ws;
  float* out = (float*)d_out;
  float* w1t = ws + OFF_W1T;
  float* w3t = ws + OFF_W3T;
  uint4* cwpk = (uint4*)(ws + OFF_CWPK);
  float* kpf = ws + OFF_KPF;
  float* sc1 = ws + OFF_SC1, *sh1 = ws + OFF_SH1;
  float* sc2 = ws + OFF_SC2, *sh2 = ws + OFF_SH2;
  float* sc3 = ws + OFF_SC3, *sh3 = ws + OFF_SH3;
  float* part = ws + OFF_PART;
  float* A = ws + OFF_A;
  float* B = ws + OFF_B;
  unsigned* F = (unsigned*)(out + NPTS*3);    // scratch in d_out's feat section

  KPArgs kpa;
  host_make_kp(kpa.p);

  prep_kernel<<<133, 256, 0, stream>>>(w1, w3, cw, kpa, w1t, w3t, cwpk, kpf);

  // fc1 (stats fused) -> finalize -> BN1-apply+ReLU+bf16-pack
  gemm128<0><<<NPTS/32, 256, 0, stream>>>(feat, w1t, nullptr, nullptr, A, part);
  bn_final<512><<<1, 1024, 0, stream>>>(part, g1, b1, sc1, sh1);
  bn1_pack<<<NPTS*64/256, 256, 0, stream>>>(A, sc1, sh1, F);

  // KPConv (MFMA, packed gather)
  kpconv_kernel<<<NPTS/4, 256, 0, stream>>>(coord, ref, F, cwpk, kpf, B);

  // BN2 stats -> finalize (apply fused into fc3 LDS stage)
  bn_stats<<<256, 128, 0, stream>>>(B, part);
  bn_final<256><<<1, 1024, 0, stream>>>(part, g2, b2, sc2, sh2);

  // fc3 (BN2-apply fused, stats fused) -> finalize
  gemm128<1><<<NPTS/32, 256, 0, stream>>>(B, w3t, sc2, sh2, A, part);
  bn_final<512><<<1, 1024, 0, stream>>>(part, g3, b3, sc3, sh3);

  // residual + ReLU + coord + offset
  final_out_kernel<<<(NPTS*NC/4 + NPTS*3/4 + 255)/256, 256, 0, stream>>>(
      feat, A, sc3, sh3, coord, offs, out);
}